// Round 8
// baseline (118.110 us; speedup 1.0000x reference)
//
#include <hip/hip_runtime.h>

// Nearest-prototype argmin: N=500k, K=256, D=64, fp32.
// R8: LDS-free B-path. The 16x16x32 B-fragment (lane (lp,lg) needs elems
// k=lg*8..+8 (+h*32) of point tile*16+lp) is loaded DIRECTLY from global as
// 4 float4/lane (wave footprint = 16 contiguous rows, L1-merged), split to
// bf16 in-register. Deletes stage ds_writes + frag ds_reads + the staging
// barrier (barrier now = merge only). Prefetch: consume q0..q3 at loop top,
// immediately issue next tile's loads -> issue->use distance = full
// iteration >= HBM latency (R7's stall: same-iteration consume). Numerics
// bit-identical to R7 (absmax=0 heritage). NBLK=1024 (R7: 2048 only bought
// prologues). Margin 0.01 + compacted-list exact-fp32 fixup unchanged.

#define DIM 64
#define NPROTO 256
#define NBLK 1024
#define MARGIN 0.01f

using f32x4  = __attribute__((ext_vector_type(4))) float;
using bf16x8 = __attribute__((ext_vector_type(8))) __bf16;

__device__ __forceinline__ void split2(float x, __bf16& h0, __bf16& h1) {
    h0 = (__bf16)x;                 // RNE; x - (float)h0 exact in fp32
    h1 = (__bf16)(x - (float)h0);   // dropped residual ~2^-18 |x|
}

__device__ __forceinline__ void split8(const float4 a, const float4 b,
                                       bf16x8& hi, bf16x8& lo) {
    const float f[8] = {a.x, a.y, a.z, a.w, b.x, b.y, b.z, b.w};
#pragma unroll
    for (int e = 0; e < 8; ++e) {
        __bf16 h0, h1;
        split2(f[e], h0, h1);
        hi[e] = h0; lo[e] = h1;
    }
}

__attribute__((amdgpu_waves_per_eu(4, 8)))
__global__ void __launch_bounds__(256)
argmin_mfma_kernel(const float* __restrict__ X,
                   const float* __restrict__ mus,
                   int* __restrict__ out,
                   unsigned* __restrict__ ws_count,
                   int* __restrict__ ws_list,
                   int use_list, int n) {
    __shared__ float s_musq[NPROTO];
    __shared__ float s_cb[2][4][16];
    __shared__ float s_cb2[2][4][16];
    __shared__ int   s_ck[2][4][16];

    const int tid = threadIdx.x;
    const int w  = tid >> 6;   // wave 0..3 -> protos [w*64, w*64+64)
    const int l  = tid & 63;
    const int lp = l & 15;     // A-row / B-col lane index
    const int lg = l >> 4;     // k-group

    // ---- per-block musq (fp32, 4-stripe order, absmax=0 heritage) ----
    {
        const float4* m4 = (const float4*)(mus + tid * DIM);
        float a0 = 0.f, a1 = 0.f, a2 = 0.f, a3 = 0.f;
#pragma unroll
        for (int q = 0; q < 16; ++q) {
            float4 v = m4[q];
            a0 = fmaf(v.x, v.x, a0); a1 = fmaf(v.y, v.y, a1);
            a2 = fmaf(v.z, v.z, a2); a3 = fmaf(v.w, v.w, a3);
        }
        s_musq[tid] = (a0 + a1) + (a2 + a3);
    }

    // ---- per-wave persistent A-frags: 64 protos x K64 x 2 levels ----
    bf16x8 amu[4][2][2];
#pragma unroll
    for (int t = 0; t < 4; ++t) {
        const int p = w * 64 + t * 16 + lp;
#pragma unroll
        for (int h = 0; h < 2; ++h) {
            const float* src = mus + (size_t)p * DIM + h * 32 + lg * 8;
            const float4 va = *(const float4*)src;
            const float4 vb = *(const float4*)(src + 4);
            split8(va, vb, amu[t][h][0], amu[t][h][1]);
        }
    }
    __syncthreads();  // s_musq visible to all waves

    // ---- tile range for this block ----
    const int ntiles = (n + 15) / 16;        // 31250
    const int q = ntiles / NBLK, rr = ntiles % NBLK;
    const int bid = blockIdx.x;
    const int t0  = bid * q + (bid < rr ? bid : rr);
    const int cnt = q + (bid < rr ? 1 : 0);

    // prologue: load tile t0's B-source floats (lane (lp,lg): row tile*16+lp,
    // floats [lg*8..+8) and [32+lg*8..+8))
    float4 q0, q1, q2, q3;
    {
        int pr = t0 * 16 + lp; pr = (pr < n) ? pr : (n - 1);
        const float* rp = X + (size_t)pr * DIM + lg * 8;
        q0 = *(const float4*)(rp);
        q1 = *(const float4*)(rp + 4);
        q2 = *(const float4*)(rp + 32);
        q3 = *(const float4*)(rp + 36);
    }

    for (int it = 0; it < cnt; ++it) {
        const int tile = t0 + it;
        const int par = it & 1;
        const bool more = (it + 1 < cnt);

        // build B-frags in-register (same values R7 read back from LDS)
        bf16x8 bx[2][2];
        split8(q0, q1, bx[0][0], bx[0][1]);
        split8(q2, q3, bx[1][0], bx[1][1]);

        // q consumed -> immediately issue next tile's loads; consumed at the
        // top of the NEXT iteration => prefetch distance = full iteration
        if (more) {
            int pn = (tile + 1) * 16 + lp; pn = (pn < n) ? pn : (n - 1);
            const float* rp = X + (size_t)pn * DIM + lg * 8;
            q0 = *(const float4*)(rp);
            q1 = *(const float4*)(rp + 4);
            q2 = *(const float4*)(rp + 32);
            q3 = *(const float4*)(rp + 36);
        }

        f32x4 acc[4] = {{0.f, 0.f, 0.f, 0.f}, {0.f, 0.f, 0.f, 0.f},
                        {0.f, 0.f, 0.f, 0.f}, {0.f, 0.f, 0.f, 0.f}};
        constexpr int PI[3] = {0, 1, 0};
        constexpr int PJ[3] = {0, 0, 1};
#pragma unroll
        for (int pp = 0; pp < 3; ++pp)
#pragma unroll
            for (int h = 0; h < 2; ++h)
#pragma unroll
                for (int t = 0; t < 4; ++t)
                    acc[t] = __builtin_amdgcn_mfma_f32_16x16x32_bf16(
                        amu[t][h][PI[pp]], bx[h][PJ[pp]], acc[t], 0, 0, 0);

        // epilogue: d2 = musq - 2*dot (x_sq const per point -> dropped);
        // in-lane top-2 over 16 slots, kk ascending -> strict < = first-min
        float b1 = 3.4e38f, b2 = 3.4e38f;
        int k1 = 0;
#pragma unroll
        for (int t = 0; t < 4; ++t)
#pragma unroll
            for (int r = 0; r < 4; ++r) {
                const int kk = w * 64 + t * 16 + lg * 4 + r;
                const float d2 = fmaf(-2.0f, acc[t][r], s_musq[kk]);
                const bool lt = d2 < b1;
                const float nb2 = lt ? b1 : fminf(d2, b2);
                b1 = lt ? d2 : b1;
                k1 = lt ? kk : k1;
                b2 = nb2;
            }
        // cross-lane over lg (lanes with same lp share a point)
#pragma unroll
        for (int m = 16; m <= 32; m <<= 1) {
            const float ob1 = __shfl_xor(b1, m);
            const float ob2 = __shfl_xor(b2, m);
            const int   ok1 = __shfl_xor(k1, m);
            const float nb2 = fminf(fmaxf(b1, ob1), fminf(b2, ob2));
            const bool take = (ob1 < b1) || (ob1 == b1 && ok1 < k1);
            b1 = take ? ob1 : b1;
            k1 = take ? ok1 : k1;
            b2 = nb2;
        }
        if (lg == 0) {
            s_cb[par][w][lp] = b1; s_cb2[par][w][lp] = b2; s_ck[par][w][lp] = k1;
        }

        __syncthreads();

        // merge 4 waves (ascending w: tie keeps lower proto) + store.
        // Reads s_cb[par]; next iteration writes s_cb[par^1] -> no race
        // (a wave cannot pass barrier(it+1) before all finish merge-read(it)).
        if (tid < 16) {
            float f1 = s_cb[par][0][tid], f2 = s_cb2[par][0][tid];
            int fk = s_ck[par][0][tid];
#pragma unroll
            for (int ww = 1; ww < 4; ++ww) {
                const float ob1 = s_cb[par][ww][tid], ob2 = s_cb2[par][ww][tid];
                const int ok1 = s_ck[par][ww][tid];
                const float nb2 = fminf(fmaxf(f1, ob1), fminf(f2, ob2));
                if (ob1 < f1) { f1 = ob1; fk = ok1; }
                f2 = nb2;
            }
            const int i = tile * 16 + tid;
            if (i < n) {
                const bool close = (f2 - f1) < MARGIN;
                if (use_list) {
                    out[i] = fk;  // clean index; flagged points go to the list
                    if (close) {
                        const unsigned idx = atomicAdd(ws_count, 1u);
                        ws_list[idx] = i;  // capacity >= n guaranteed by host
                    }
                } else {
                    out[i] = (int)((unsigned)fk | (close ? 0x80000000u : 0u));
                }
            }
        }
    }
}

// Exact-fp32 wave-cooperative recompute of one point (R2-proven order).
__device__ __forceinline__ int recompute_point(const float* __restrict__ X,
                                               const float* __restrict__ mus,
                                               int pt, int l) {
    const float4* xr = (const float4*)(X + (size_t)pt * DIM);
    float4 xv[16];
    float xa0 = 0.f, xa1 = 0.f, xa2 = 0.f, xa3 = 0.f;
#pragma unroll
    for (int qq = 0; qq < 16; ++qq) {
        xv[qq] = xr[qq];
        xa0 = fmaf(xv[qq].x, xv[qq].x, xa0);
        xa1 = fmaf(xv[qq].y, xv[qq].y, xa1);
        xa2 = fmaf(xv[qq].z, xv[qq].z, xa2);
        xa3 = fmaf(xv[qq].w, xv[qq].w, xa3);
    }
    const float xsq = (xa0 + xa1) + (xa2 + xa3);
    float b1 = 3.4e38f; int k1 = 0;
#pragma unroll
    for (int e = 0; e < 4; ++e) {
        const int p = l * 4 + e;
        const float4* mr = (const float4*)(mus + (size_t)p * DIM);
        float d0 = 0.f, d1 = 0.f, d2a = 0.f, d3 = 0.f;
        float q0 = 0.f, q1 = 0.f, q2 = 0.f, q3 = 0.f;
#pragma unroll
        for (int qq = 0; qq < 16; ++qq) {
            const float4 mv = mr[qq];
            d0 = fmaf(mv.x, xv[qq].x, d0);
            d1 = fmaf(mv.y, xv[qq].y, d1);
            d2a = fmaf(mv.z, xv[qq].z, d2a);
            d3 = fmaf(mv.w, xv[qq].w, d3);
            q0 = fmaf(mv.x, mv.x, q0);
            q1 = fmaf(mv.y, mv.y, q1);
            q2 = fmaf(mv.z, mv.z, q2);
            q3 = fmaf(mv.w, mv.w, q3);
        }
        const float dot = (d0 + d1) + (d2a + d3);
        const float msq = (q0 + q1) + (q2 + q3);
        const float dd = (xsq - 2.0f * dot) + msq;
        if (dd < b1) { b1 = dd; k1 = p; }
    }
#pragma unroll
    for (int mm = 1; mm < 64; mm <<= 1) {
        const float ob = __shfl_xor(b1, mm);
        const int ok = __shfl_xor(k1, mm);
        if (ob < b1 || (ob == b1 && ok < k1)) { b1 = ob; k1 = ok; }
    }
    return k1;
}

// List-driven fixup: one wave per flagged point, grid-stride over the list.
__global__ void __launch_bounds__(256)
fixup_list_kernel(const float* __restrict__ X, const float* __restrict__ mus,
                  const unsigned* __restrict__ ws_count,
                  const int* __restrict__ ws_list, int* __restrict__ out) {
    const int gw = (int)((blockIdx.x * blockDim.x + threadIdx.x) >> 6);
    const int l  = threadIdx.x & 63;
    const int NW = (int)((gridDim.x * blockDim.x) >> 6);
    const int nf = (int)*ws_count;
    for (int j = gw; j < nf; j += NW) {
        const int pt = ws_list[j];
        const int k1 = recompute_point(X, mus, pt, l);
        if (l == 0) out[pt] = k1;
    }
}

// Fallback scan fixup (flag bit 31 in out), used if ws too small.
__global__ void __launch_bounds__(256)
fixup_scan_kernel(const float* __restrict__ X, const float* __restrict__ mus,
                  int* __restrict__ out, int n) {
    const int gw = (int)((blockIdx.x * blockDim.x + threadIdx.x) >> 6);
    const int l  = threadIdx.x & 63;
    const int NW = (int)((gridDim.x * blockDim.x) >> 6);
    const int chunk = (n + NW - 1) / NW;
    const int base = gw * chunk;
    const int end  = (base + chunk < n) ? (base + chunk) : n;
    for (int s = base; s < end; s += 64) {
        const int i = s + l;
        const int v = (i < end) ? out[i] : 0;
        const bool fl = (i < end) && ((unsigned)v & 0x80000000u);
        unsigned long long m = __ballot(fl);
        while (m) {
            const int src = (int)__ffsll((unsigned long long)m) - 1;
            m &= m - 1;
            const int pt = __shfl(i, src);
            const int k1 = recompute_point(X, mus, pt, l);
            if (l == 0) out[pt] = k1;
        }
    }
}

extern "C" void kernel_launch(void* const* d_in, const int* in_sizes, int n_in,
                              void* d_out, int out_size, void* d_ws, size_t ws_size,
                              hipStream_t stream) {
    const float* X = (const float*)d_in[0];
    const float* mus = (const float*)d_in[1];
    int* out = (int*)d_out;
    const int n = in_sizes[0] / DIM;  // 500000

    unsigned* ws_count = (unsigned*)d_ws;
    int* ws_list = (int*)((char*)d_ws + 16);
    const int use_list = (ws_size >= 16 + (size_t)n * 4) ? 1 : 0;

    if (use_list) {
        hipMemsetAsync(d_ws, 0, 16, stream);  // reset append counter
    }

    argmin_mfma_kernel<<<NBLK, 256, 0, stream>>>(X, mus, out, ws_count,
                                                 ws_list, use_list, n);
    if (use_list) {
        fixup_list_kernel<<<256, 256, 0, stream>>>(X, mus, ws_count, ws_list,
                                                   out);
    } else {
        fixup_scan_kernel<<<512, 256, 0, stream>>>(X, mus, out, n);
    }
}

// Round 9
// 92.342 us; speedup vs baseline: 1.2790x; 1.2790x over previous
//
#include <hip/hip_runtime.h>

// Nearest-prototype argmin: N=500k, K=256, D=64, fp32.
// R9: R7's proven structure (cooperative LDS staging, 3-pass bf16 MFMA,
// margin 0.01 + compacted-list exact-fp32 fixup) with per-tile overhead
// amortized 4x: 64 points per iteration (4 sub-tiles of 16), ONE barrier +
// ONE 64-lane merge per iteration, prefetch issued at iteration top and
// consumed by staging at iteration end (issue->use >= 1500 cyc). R8 lesson:
// no per-wave in-register B split (spilled, WRITE_SIZE 8 MB); staging split
// stays cooperative. waves_per_eu(3,4) so the 4xfloat4 prefetch fits
// without spill.

#define DIM 64
#define NPROTO 256
#define NBLK 1024
#define SUBT 4
#define PPI 64   // points per iteration = SUBT * 16
#define MARGIN 0.01f

using f32x4  = __attribute__((ext_vector_type(4))) float;
using bf16x8 = __attribute__((ext_vector_type(8))) __bf16;
using bf16x4 = __attribute__((ext_vector_type(4))) __bf16;

__device__ __forceinline__ void split2(float x, __bf16& h0, __bf16& h1) {
    h0 = (__bf16)x;                 // RNE; x - (float)h0 exact in fp32
    h1 = (__bf16)(x - (float)h0);   // dropped residual ~2^-18 |x|
}

// split one float4 and write both levels into a sub-tile's LDS plane.
// lvl0 points at s_x[buf][j][0][srow][0]; level stride = 16*64 bf16.
__device__ __forceinline__ void stage_one(__bf16* lvl0, float4 v, int wgi) {
    bf16x4 w0, w1;
    const float xf[4] = {v.x, v.y, v.z, v.w};
#pragma unroll
    for (int e = 0; e < 4; ++e) {
        __bf16 h0, h1;
        split2(xf[e], h0, h1);
        w0[e] = h0; w1[e] = h1;
    }
    ((bf16x4*)lvl0)[wgi] = w0;
    ((bf16x4*)(lvl0 + 16 * 64))[wgi] = w1;
}

__device__ __forceinline__ float4 loadx(const float* __restrict__ X, int t,
                                        int j, int srow, int spart, int n) {
    int pr = t * PPI + j * 16 + srow;
    pr = (pr < n) ? pr : (n - 1);   // OOB rows clamp; store is guarded
    return *(const float4*)(X + (size_t)pr * DIM + spart * 4);
}

__attribute__((amdgpu_waves_per_eu(3, 4)))
__global__ void __launch_bounds__(256)
argmin_mfma_kernel(const float* __restrict__ X,
                   const float* __restrict__ mus,
                   int* __restrict__ out,
                   unsigned* __restrict__ ws_count,
                   int* __restrict__ ws_list,
                   int use_list, int n) {
    __shared__ __align__(16) __bf16 s_x[2][SUBT][2][16][64];  // 32 KB
    __shared__ float s_musq[NPROTO];
    __shared__ float s_cb[2][SUBT][4][16];
    __shared__ float s_cb2[2][SUBT][4][16];
    __shared__ int   s_ck[2][SUBT][4][16];

    const int tid = threadIdx.x;
    const int w  = tid >> 6;   // wave 0..3 -> protos [w*64, w*64+64)
    const int l  = tid & 63;
    const int lp = l & 15;     // A-row / B-col lane index
    const int lg = l >> 4;     // k-group

    // ---- per-block musq (fp32, 4-stripe order, absmax=0 heritage) ----
    {
        const float4* m4 = (const float4*)(mus + tid * DIM);
        float a0 = 0.f, a1 = 0.f, a2 = 0.f, a3 = 0.f;
#pragma unroll
        for (int q = 0; q < 16; ++q) {
            float4 v = m4[q];
            a0 = fmaf(v.x, v.x, a0); a1 = fmaf(v.y, v.y, a1);
            a2 = fmaf(v.z, v.z, a2); a3 = fmaf(v.w, v.w, a3);
        }
        s_musq[tid] = (a0 + a1) + (a2 + a3);
    }

    // ---- per-wave persistent A-frags: 64 protos x K64 x 2 levels ----
    bf16x8 amu[4][2][2];
#pragma unroll
    for (int t = 0; t < 4; ++t) {
        const int p = w * 64 + t * 16 + lp;
#pragma unroll
        for (int h = 0; h < 2; ++h) {
            const float* src = mus + (size_t)p * DIM + h * 32 + lg * 8;
            const float4 va = *(const float4*)src;
            const float4 vb = *(const float4*)(src + 4);
            const float xs[8] = {va.x, va.y, va.z, va.w, vb.x, vb.y, vb.z, vb.w};
            bf16x8 m0, m1;
#pragma unroll
            for (int e = 0; e < 8; ++e) {
                __bf16 h0, h1;
                split2(xs[e], h0, h1);
                m0[e] = h0; m1[e] = h1;
            }
            amu[t][h][0] = m0; amu[t][h][1] = m1;
        }
    }

    // ---- 64-point tile range for this block ----
    const int ntiles = (n + PPI - 1) / PPI;   // 7813
    const int q = ntiles / NBLK, rr = ntiles % NBLK;
    const int bid = blockIdx.x;
    const int t0  = bid * q + (bid < rr ? bid : rr);
    const int cnt = q + (bid < rr ? 1 : 0);

    const int srow = tid >> 4, spart = tid & 15;
    const int wgi = spart ^ ((srow & 7) << 1);  // swizzled 8B-granule index

    // prologue: load + stage tile t0 into buf 0 (all 4 sub-tiles)
    float4 xn0 = loadx(X, t0, 0, srow, spart, n);
    float4 xn1 = loadx(X, t0, 1, srow, spart, n);
    float4 xn2 = loadx(X, t0, 2, srow, spart, n);
    float4 xn3 = loadx(X, t0, 3, srow, spart, n);
    stage_one(&s_x[0][0][0][srow][0], xn0, wgi);
    stage_one(&s_x[0][1][0][srow][0], xn1, wgi);
    stage_one(&s_x[0][2][0][srow][0], xn2, wgi);
    stage_one(&s_x[0][3][0][srow][0], xn3, wgi);
    __syncthreads();  // also publishes s_musq

    for (int it = 0; it < cnt; ++it) {
        const int tile = t0 + it;
        const int par = it & 1;
        const bool more = (it + 1 < cnt);

        // issue next tile's loads at iteration TOP; consumed by staging at
        // iteration END -> issue->use spans 96 MFMAs + 4 epilogues
        if (more) {
            xn0 = loadx(X, tile + 1, 0, srow, spart, n);
            xn1 = loadx(X, tile + 1, 1, srow, spart, n);
            xn2 = loadx(X, tile + 1, 2, srow, spart, n);
            xn3 = loadx(X, tile + 1, 3, srow, spart, n);
        }

#pragma unroll
        for (int j = 0; j < SUBT; ++j) {
            // B-frags from s_x[par][j] (swizzled 16B reads)
            bf16x8 bx[2][2];
#pragma unroll
            for (int h = 0; h < 2; ++h)
#pragma unroll
                for (int v = 0; v < 2; ++v)
                    bx[h][v] = ((const bf16x8*)&s_x[par][j][v][lp][0])
                                   [(h * 4 + lg) ^ (lp & 7)];

            f32x4 acc[4] = {{0.f, 0.f, 0.f, 0.f}, {0.f, 0.f, 0.f, 0.f},
                            {0.f, 0.f, 0.f, 0.f}, {0.f, 0.f, 0.f, 0.f}};
            constexpr int PI[3] = {0, 1, 0};
            constexpr int PJ[3] = {0, 0, 1};
#pragma unroll
            for (int pp = 0; pp < 3; ++pp)
#pragma unroll
                for (int h = 0; h < 2; ++h)
#pragma unroll
                    for (int t = 0; t < 4; ++t)
                        acc[t] = __builtin_amdgcn_mfma_f32_16x16x32_bf16(
                            amu[t][h][PI[pp]], bx[h][PJ[pp]], acc[t], 0, 0, 0);

            // epilogue: d2 = musq - 2*dot; in-lane top-2 over 16 slots,
            // kk ascending -> strict < = first-min (np.argmin)
            float b1 = 3.4e38f, b2 = 3.4e38f;
            int k1 = 0;
#pragma unroll
            for (int t = 0; t < 4; ++t)
#pragma unroll
                for (int r = 0; r < 4; ++r) {
                    const int kk = w * 64 + t * 16 + lg * 4 + r;
                    const float d2 = fmaf(-2.0f, acc[t][r], s_musq[kk]);
                    const bool lt = d2 < b1;
                    const float nb2 = lt ? b1 : fminf(d2, b2);
                    b1 = lt ? d2 : b1;
                    k1 = lt ? kk : k1;
                    b2 = nb2;
                }
            // cross-lane over lg (lanes with same lp share a point)
#pragma unroll
            for (int m = 16; m <= 32; m <<= 1) {
                const float ob1 = __shfl_xor(b1, m);
                const float ob2 = __shfl_xor(b2, m);
                const int   ok1 = __shfl_xor(k1, m);
                const float nb2 = fminf(fmaxf(b1, ob1), fminf(b2, ob2));
                const bool take = (ob1 < b1) || (ob1 == b1 && ok1 < k1);
                b1 = take ? ob1 : b1;
                k1 = take ? ok1 : k1;
                b2 = nb2;
            }
            if (lg == 0) {
                s_cb[par][j][w][lp] = b1;
                s_cb2[par][j][w][lp] = b2;
                s_ck[par][j][w][lp] = k1;
            }
        }

        // cooperative stage of next tile into the other buffer
        if (more) {
            stage_one(&s_x[par ^ 1][0][0][srow][0], xn0, wgi);
            stage_one(&s_x[par ^ 1][1][0][srow][0], xn1, wgi);
            stage_one(&s_x[par ^ 1][2][0][srow][0], xn2, wgi);
            stage_one(&s_x[par ^ 1][3][0][srow][0], xn3, wgi);
        }

        __syncthreads();

        // merge 4 waves for all 64 points (wave 0, one lane per point).
        // Reads s_cb[par]; others write s_cb[par^1] next iter -> no race;
        // they re-write s_cb[par] only after barrier(it+1), which wave 0
        // reaches after finishing this merge.
        if (tid < PPI) {
            const int j = tid >> 4, c = tid & 15;
            float f1 = s_cb[par][j][0][c], f2 = s_cb2[par][j][0][c];
            int fk = s_ck[par][j][0][c];
#pragma unroll
            for (int ww = 1; ww < 4; ++ww) {
                const float ob1 = s_cb[par][j][ww][c];
                const float ob2 = s_cb2[par][j][ww][c];
                const int   ok1 = s_ck[par][j][ww][c];
                const float nb2 = fminf(fmaxf(f1, ob1), fminf(f2, ob2));
                if (ob1 < f1) { f1 = ob1; fk = ok1; }
                f2 = nb2;
            }
            const int i = tile * PPI + tid;
            if (i < n) {
                const bool close = (f2 - f1) < MARGIN;
                if (use_list) {
                    out[i] = fk;  // clean index; flagged points go to the list
                    if (close) {
                        const unsigned idx = atomicAdd(ws_count, 1u);
                        ws_list[idx] = i;  // capacity >= n guaranteed by host
                    }
                } else {
                    out[i] = (int)((unsigned)fk | (close ? 0x80000000u : 0u));
                }
            }
        }
    }
}

// Exact-fp32 wave-cooperative recompute of one point (R2-proven order).
__device__ __forceinline__ int recompute_point(const float* __restrict__ X,
                                               const float* __restrict__ mus,
                                               int pt, int l) {
    const float4* xr = (const float4*)(X + (size_t)pt * DIM);
    float4 xv[16];
    float xa0 = 0.f, xa1 = 0.f, xa2 = 0.f, xa3 = 0.f;
#pragma unroll
    for (int qq = 0; qq < 16; ++qq) {
        xv[qq] = xr[qq];
        xa0 = fmaf(xv[qq].x, xv[qq].x, xa0);
        xa1 = fmaf(xv[qq].y, xv[qq].y, xa1);
        xa2 = fmaf(xv[qq].z, xv[qq].z, xa2);
        xa3 = fmaf(xv[qq].w, xv[qq].w, xa3);
    }
    const float xsq = (xa0 + xa1) + (xa2 + xa3);
    float b1 = 3.4e38f; int k1 = 0;
#pragma unroll
    for (int e = 0; e < 4; ++e) {
        const int p = l * 4 + e;
        const float4* mr = (const float4*)(mus + (size_t)p * DIM);
        float d0 = 0.f, d1 = 0.f, d2a = 0.f, d3 = 0.f;
        float q0 = 0.f, q1 = 0.f, q2 = 0.f, q3 = 0.f;
#pragma unroll
        for (int qq = 0; qq < 16; ++qq) {
            const float4 mv = mr[qq];
            d0 = fmaf(mv.x, xv[qq].x, d0);
            d1 = fmaf(mv.y, xv[qq].y, d1);
            d2a = fmaf(mv.z, xv[qq].z, d2a);
            d3 = fmaf(mv.w, xv[qq].w, d3);
            q0 = fmaf(mv.x, mv.x, q0);
            q1 = fmaf(mv.y, mv.y, q1);
            q2 = fmaf(mv.z, mv.z, q2);
            q3 = fmaf(mv.w, mv.w, q3);
        }
        const float dot = (d0 + d1) + (d2a + d3);
        const float msq = (q0 + q1) + (q2 + q3);
        const float dd = (xsq - 2.0f * dot) + msq;
        if (dd < b1) { b1 = dd; k1 = p; }
    }
#pragma unroll
    for (int mm = 1; mm < 64; mm <<= 1) {
        const float ob = __shfl_xor(b1, mm);
        const int ok = __shfl_xor(k1, mm);
        if (ob < b1 || (ob == b1 && ok < k1)) { b1 = ob; k1 = ok; }
    }
    return k1;
}

// List-driven fixup: one wave per flagged point, grid-stride over the list.
__global__ void __launch_bounds__(256)
fixup_list_kernel(const float* __restrict__ X, const float* __restrict__ mus,
                  const unsigned* __restrict__ ws_count,
                  const int* __restrict__ ws_list, int* __restrict__ out) {
    const int gw = (int)((blockIdx.x * blockDim.x + threadIdx.x) >> 6);
    const int l  = threadIdx.x & 63;
    const int NW = (int)((gridDim.x * blockDim.x) >> 6);
    const int nf = (int)*ws_count;
    for (int j = gw; j < nf; j += NW) {
        const int pt = ws_list[j];
        const int k1 = recompute_point(X, mus, pt, l);
        if (l == 0) out[pt] = k1;
    }
}

// Fallback scan fixup (flag bit 31 in out), used if ws too small.
__global__ void __launch_bounds__(256)
fixup_scan_kernel(const float* __restrict__ X, const float* __restrict__ mus,
                  int* __restrict__ out, int n) {
    const int gw = (int)((blockIdx.x * blockDim.x + threadIdx.x) >> 6);
    const int l  = threadIdx.x & 63;
    const int NW = (int)((gridDim.x * blockDim.x) >> 6);
    const int chunk = (n + NW - 1) / NW;
    const int base = gw * chunk;
    const int end  = (base + chunk < n) ? (base + chunk) : n;
    for (int s = base; s < end; s += 64) {
        const int i = s + l;
        const int v = (i < end) ? out[i] : 0;
        const bool fl = (i < end) && ((unsigned)v & 0x80000000u);
        unsigned long long m = __ballot(fl);
        while (m) {
            const int src = (int)__ffsll((unsigned long long)m) - 1;
            m &= m - 1;
            const int pt = __shfl(i, src);
            const int k1 = recompute_point(X, mus, pt, l);
            if (l == 0) out[pt] = k1;
        }
    }
}

extern "C" void kernel_launch(void* const* d_in, const int* in_sizes, int n_in,
                              void* d_out, int out_size, void* d_ws, size_t ws_size,
                              hipStream_t stream) {
    const float* X = (const float*)d_in[0];
    const float* mus = (const float*)d_in[1];
    int* out = (int*)d_out;
    const int n = in_sizes[0] / DIM;  // 500000

    unsigned* ws_count = (unsigned*)d_ws;
    int* ws_list = (int*)((char*)d_ws + 16);
    const int use_list = (ws_size >= 16 + (size_t)n * 4) ? 1 : 0;

    if (use_list) {
        hipMemsetAsync(d_ws, 0, 16, stream);  // reset append counter
    }

    argmin_mfma_kernel<<<NBLK, 256, 0, stream>>>(X, mus, out, ws_count,
                                                 ws_list, use_list, n);
    if (use_list) {
        fixup_list_kernel<<<256, 256, 0, stream>>>(X, mus, ws_count, ws_list,
                                                   out);
    } else {
        fixup_scan_kernel<<<512, 256, 0, stream>>>(X, mus, out, n);
    }
}

// Round 10
// 88.311 us; speedup vs baseline: 1.3374x; 1.0456x over previous
//
#include <hip/hip_runtime.h>

// Nearest-prototype argmin: N=500k, K=256, D=64, fp32.
// R10 = R9 structure (64 pts/iter, 1 barrier, cooperative staging, 3-pass
// bf16 MFMA, margin + compacted-list exact-fp32 fixup) with the epilogue
// attacked (R9: VALUBusy 45% ~= 1.8x MfmaUtil, serial top-2 chain):
//  - MFMA C seeded with -musq/2 -> argmax(acc) == argmin(d2); kills the
//    per-slot fma, acc zero-init, and per-slot musq LDS reads.
//  - top-2+index via a balanced tree (v_max3-fusable), depth ~12 vs ~64.
//  - margin in acc units = 0.005 (d2 gap = 2x acc gap).
// Fixup grid 512.

#define DIM 64
#define NPROTO 256
#define NBLK 1024
#define SUBT 4
#define PPI 64   // points per iteration = SUBT * 16
#define MARGIN_ACC 0.005f   // = 0.01 in d2 units

using f32x4  = __attribute__((ext_vector_type(4))) float;
using bf16x8 = __attribute__((ext_vector_type(8))) __bf16;
using bf16x4 = __attribute__((ext_vector_type(4))) __bf16;

__device__ __forceinline__ void split2(float x, __bf16& h0, __bf16& h1) {
    h0 = (__bf16)x;                 // RNE; x - (float)h0 exact in fp32
    h1 = (__bf16)(x - (float)h0);   // dropped residual ~2^-18 |x|
}

// split one float4 and write both levels into a sub-tile's LDS plane.
__device__ __forceinline__ void stage_one(__bf16* lvl0, float4 v, int wgi) {
    bf16x4 w0, w1;
    const float xf[4] = {v.x, v.y, v.z, v.w};
#pragma unroll
    for (int e = 0; e < 4; ++e) {
        __bf16 h0, h1;
        split2(xf[e], h0, h1);
        w0[e] = h0; w1[e] = h1;
    }
    ((bf16x4*)lvl0)[wgi] = w0;
    ((bf16x4*)(lvl0 + 16 * 64))[wgi] = w1;
}

__device__ __forceinline__ float4 loadx(const float* __restrict__ X, int t,
                                        int j, int srow, int spart, int n) {
    int pr = t * PPI + j * 16 + srow;
    pr = (pr < n) ? pr : (n - 1);   // OOB rows clamp; store is guarded
    return *(const float4*)(X + (size_t)pr * DIM + spart * 4);
}

__attribute__((amdgpu_waves_per_eu(3, 4)))
__global__ void __launch_bounds__(256)
argmin_mfma_kernel(const float* __restrict__ X,
                   const float* __restrict__ mus,
                   int* __restrict__ out,
                   unsigned* __restrict__ ws_count,
                   int* __restrict__ ws_list,
                   int use_list, int n) {
    __shared__ __align__(16) __bf16 s_x[2][SUBT][2][16][64];  // 32 KB
    __shared__ float s_musq[NPROTO];   // holds -0.5*musq
    __shared__ float s_cb[2][SUBT][4][16];
    __shared__ float s_cb2[2][SUBT][4][16];
    __shared__ int   s_ck[2][SUBT][4][16];

    const int tid = threadIdx.x;
    const int w  = tid >> 6;   // wave 0..3 -> protos [w*64, w*64+64)
    const int l  = tid & 63;
    const int lp = l & 15;     // A-row / B-col lane index
    const int lg = l >> 4;     // k-group

    // ---- per-block -musq/2 (fp32, 4-stripe order, absmax=0 heritage) ----
    {
        const float4* m4 = (const float4*)(mus + tid * DIM);
        float a0 = 0.f, a1 = 0.f, a2 = 0.f, a3 = 0.f;
#pragma unroll
        for (int q = 0; q < 16; ++q) {
            float4 v = m4[q];
            a0 = fmaf(v.x, v.x, a0); a1 = fmaf(v.y, v.y, a1);
            a2 = fmaf(v.z, v.z, a2); a3 = fmaf(v.w, v.w, a3);
        }
        s_musq[tid] = -0.5f * ((a0 + a1) + (a2 + a3));
    }

    // ---- per-wave persistent A-frags: 64 protos x K64 x 2 levels ----
    bf16x8 amu[4][2][2];
#pragma unroll
    for (int t = 0; t < 4; ++t) {
        const int p = w * 64 + t * 16 + lp;
#pragma unroll
        for (int h = 0; h < 2; ++h) {
            const float* src = mus + (size_t)p * DIM + h * 32 + lg * 8;
            const float4 va = *(const float4*)src;
            const float4 vb = *(const float4*)(src + 4);
            const float xs[8] = {va.x, va.y, va.z, va.w, vb.x, vb.y, vb.z, vb.w};
            bf16x8 m0, m1;
#pragma unroll
            for (int e = 0; e < 8; ++e) {
                __bf16 h0, h1;
                split2(xs[e], h0, h1);
                m0[e] = h0; m1[e] = h1;
            }
            amu[t][h][0] = m0; amu[t][h][1] = m1;
        }
    }

    // ---- 64-point tile range for this block ----
    const int ntiles = (n + PPI - 1) / PPI;   // 7813
    const int q = ntiles / NBLK, rr = ntiles % NBLK;
    const int bid = blockIdx.x;
    const int t0  = bid * q + (bid < rr ? bid : rr);
    const int cnt = q + (bid < rr ? 1 : 0);

    const int srow = tid >> 4, spart = tid & 15;
    const int wgi = spart ^ ((srow & 7) << 1);  // swizzled 8B-granule index

    // prologue: load + stage tile t0 into buf 0 (all 4 sub-tiles)
    float4 xn0 = loadx(X, t0, 0, srow, spart, n);
    float4 xn1 = loadx(X, t0, 1, srow, spart, n);
    float4 xn2 = loadx(X, t0, 2, srow, spart, n);
    float4 xn3 = loadx(X, t0, 3, srow, spart, n);
    stage_one(&s_x[0][0][0][srow][0], xn0, wgi);
    stage_one(&s_x[0][1][0][srow][0], xn1, wgi);
    stage_one(&s_x[0][2][0][srow][0], xn2, wgi);
    stage_one(&s_x[0][3][0][srow][0], xn3, wgi);
    __syncthreads();  // publishes s_musq + tile 0

    // C-seed fragments: mh[t][r] = -0.5*musq for this lane's 16 slots
    const int kbase = w * 64 + lg * 4;
    f32x4 mh[4];
#pragma unroll
    for (int t = 0; t < 4; ++t)
#pragma unroll
        for (int r = 0; r < 4; ++r)
            mh[t][r] = s_musq[kbase + t * 16 + r];

    for (int it = 0; it < cnt; ++it) {
        const int tile = t0 + it;
        const int par = it & 1;
        const bool more = (it + 1 < cnt);

        // issue next tile's loads at iteration TOP; consumed by staging at
        // iteration END -> issue->use spans 96 MFMAs + 4 epilogues
        if (more) {
            xn0 = loadx(X, tile + 1, 0, srow, spart, n);
            xn1 = loadx(X, tile + 1, 1, srow, spart, n);
            xn2 = loadx(X, tile + 1, 2, srow, spart, n);
            xn3 = loadx(X, tile + 1, 3, srow, spart, n);
        }

#pragma unroll
        for (int j = 0; j < SUBT; ++j) {
            // B-frags from s_x[par][j] (swizzled 16B reads)
            bf16x8 bx[2][2];
#pragma unroll
            for (int h = 0; h < 2; ++h)
#pragma unroll
                for (int v = 0; v < 2; ++v)
                    bx[h][v] = ((const bf16x8*)&s_x[par][j][v][lp][0])
                                   [(h * 4 + lg) ^ (lp & 7)];

            // acc = dot - musq/2 : pass (pp0,h0) seeds with mh, rest
            // accumulate; same (pp,h) order as R9 (absmax=0 heritage).
            f32x4 acc[4];
#pragma unroll
            for (int t = 0; t < 4; ++t)
                acc[t] = __builtin_amdgcn_mfma_f32_16x16x32_bf16(
                    amu[t][0][0], bx[0][0], mh[t], 0, 0, 0);
#pragma unroll
            for (int t = 0; t < 4; ++t)
                acc[t] = __builtin_amdgcn_mfma_f32_16x16x32_bf16(
                    amu[t][1][0], bx[1][0], acc[t], 0, 0, 0);
            constexpr int PI[2] = {1, 0};
            constexpr int PJ[2] = {0, 1};
#pragma unroll
            for (int pp = 0; pp < 2; ++pp)
#pragma unroll
                for (int h = 0; h < 2; ++h)
#pragma unroll
                    for (int t = 0; t < 4; ++t)
                        acc[t] = __builtin_amdgcn_mfma_f32_16x16x32_bf16(
                            amu[t][h][PI[pp]], bx[h][PJ[pp]], acc[t], 0, 0, 0);

            // ---- tree-based top-2 + argmax over 16 slots ----
            // slot i = t*4+r -> kk = kbase + (i>>2)*16 + (i&3); i ascending
            // <=> kk ascending, so strict > keeps the lower index (np.argmin).
            float m1[8], m2[8];
            int   ka[8];
#pragma unroll
            for (int p = 0; p < 8; ++p) {
                const int t = p >> 1, rbase = (p & 1) * 2;
                const float da = acc[t][rbase], db = acc[t][rbase + 1];
                const bool gt = db > da;
                m1[p] = gt ? db : da;
                m2[p] = gt ? da : db;
                ka[p] = kbase + t * 16 + (gt ? rbase + 1 : rbase);
            }
#pragma unroll
            for (int lvl = 0; lvl < 3; ++lvl) {
                const int step = 1 << lvl;        // merge A=p, B=p+step
#pragma unroll
                for (int p = 0; p < 8; p += 2 * step) {
                    const int pb = p + step;
                    const bool gt = m1[pb] > m1[p];
                    const float lo = fminf(m1[p], m1[pb]);
                    m1[p] = gt ? m1[pb] : m1[p];
                    ka[p] = gt ? ka[pb] : ka[p];
                    m2[p] = fmaxf(fmaxf(lo, m2[p]), m2[pb]);  // v_max3
                }
            }
            float b1 = m1[0], b2 = m2[0];
            int k1 = ka[0];

            // cross-lane over lg (lanes with same lp share a point)
#pragma unroll
            for (int m = 16; m <= 32; m <<= 1) {
                const float ob1 = __shfl_xor(b1, m);
                const float ob2 = __shfl_xor(b2, m);
                const int   ok1 = __shfl_xor(k1, m);
                const float nb2 = fmaxf(fminf(b1, ob1), fmaxf(b2, ob2));
                const bool take = (ob1 > b1) || (ob1 == b1 && ok1 < k1);
                b1 = take ? ob1 : b1;
                k1 = take ? ok1 : k1;
                b2 = nb2;
            }
            if (lg == 0) {
                s_cb[par][j][w][lp] = b1;
                s_cb2[par][j][w][lp] = b2;
                s_ck[par][j][w][lp] = k1;
            }
        }

        // cooperative stage of next tile into the other buffer
        if (more) {
            stage_one(&s_x[par ^ 1][0][0][srow][0], xn0, wgi);
            stage_one(&s_x[par ^ 1][1][0][srow][0], xn1, wgi);
            stage_one(&s_x[par ^ 1][2][0][srow][0], xn2, wgi);
            stage_one(&s_x[par ^ 1][3][0][srow][0], xn3, wgi);
        }

        __syncthreads();

        // merge 4 waves for all 64 points (wave 0, one lane per point).
        // max semantics: strict > keeps lower wave (= lower proto indices).
        if (tid < PPI) {
            const int j = tid >> 4, c = tid & 15;
            float f1 = s_cb[par][j][0][c], f2 = s_cb2[par][j][0][c];
            int fk = s_ck[par][j][0][c];
#pragma unroll
            for (int ww = 1; ww < 4; ++ww) {
                const float ob1 = s_cb[par][j][ww][c];
                const float ob2 = s_cb2[par][j][ww][c];
                const int   ok1 = s_ck[par][j][ww][c];
                const float nb2 = fmaxf(fminf(f1, ob1), fmaxf(f2, ob2));
                if (ob1 > f1) { f1 = ob1; fk = ok1; }
                f2 = nb2;
            }
            const int i = tile * PPI + tid;
            if (i < n) {
                const bool close = (f1 - f2) < MARGIN_ACC;
                if (use_list) {
                    out[i] = fk;  // clean index; flagged points go to the list
                    if (close) {
                        const unsigned idx = atomicAdd(ws_count, 1u);
                        ws_list[idx] = i;  // capacity >= n guaranteed by host
                    }
                } else {
                    out[i] = (int)((unsigned)fk | (close ? 0x80000000u : 0u));
                }
            }
        }
    }
}

// Exact-fp32 wave-cooperative recompute of one point (R2-proven order).
__device__ __forceinline__ int recompute_point(const float* __restrict__ X,
                                               const float* __restrict__ mus,
                                               int pt, int l) {
    const float4* xr = (const float4*)(X + (size_t)pt * DIM);
    float4 xv[16];
    float xa0 = 0.f, xa1 = 0.f, xa2 = 0.f, xa3 = 0.f;
#pragma unroll
    for (int qq = 0; qq < 16; ++qq) {
        xv[qq] = xr[qq];
        xa0 = fmaf(xv[qq].x, xv[qq].x, xa0);
        xa1 = fmaf(xv[qq].y, xv[qq].y, xa1);
        xa2 = fmaf(xv[qq].z, xv[qq].z, xa2);
        xa3 = fmaf(xv[qq].w, xv[qq].w, xa3);
    }
    const float xsq = (xa0 + xa1) + (xa2 + xa3);
    float b1 = 3.4e38f; int k1 = 0;
#pragma unroll
    for (int e = 0; e < 4; ++e) {
        const int p = l * 4 + e;
        const float4* mr = (const float4*)(mus + (size_t)p * DIM);
        float d0 = 0.f, d1 = 0.f, d2a = 0.f, d3 = 0.f;
        float q0 = 0.f, q1 = 0.f, q2 = 0.f, q3 = 0.f;
#pragma unroll
        for (int qq = 0; qq < 16; ++qq) {
            const float4 mv = mr[qq];
            d0 = fmaf(mv.x, xv[qq].x, d0);
            d1 = fmaf(mv.y, xv[qq].y, d1);
            d2a = fmaf(mv.z, xv[qq].z, d2a);
            d3 = fmaf(mv.w, xv[qq].w, d3);
            q0 = fmaf(mv.x, mv.x, q0);
            q1 = fmaf(mv.y, mv.y, q1);
            q2 = fmaf(mv.z, mv.z, q2);
            q3 = fmaf(mv.w, mv.w, q3);
        }
        const float dot = (d0 + d1) + (d2a + d3);
        const float msq = (q0 + q1) + (q2 + q3);
        const float dd = (xsq - 2.0f * dot) + msq;
        if (dd < b1) { b1 = dd; k1 = p; }
    }
#pragma unroll
    for (int mm = 1; mm < 64; mm <<= 1) {
        const float ob = __shfl_xor(b1, mm);
        const int ok = __shfl_xor(k1, mm);
        if (ob < b1 || (ob == b1 && ok < k1)) { b1 = ob; k1 = ok; }
    }
    return k1;
}

// List-driven fixup: one wave per flagged point, grid-stride over the list.
__global__ void __launch_bounds__(256)
fixup_list_kernel(const float* __restrict__ X, const float* __restrict__ mus,
                  const unsigned* __restrict__ ws_count,
                  const int* __restrict__ ws_list, int* __restrict__ out) {
    const int gw = (int)((blockIdx.x * blockDim.x + threadIdx.x) >> 6);
    const int l  = threadIdx.x & 63;
    const int NW = (int)((gridDim.x * blockDim.x) >> 6);
    const int nf = (int)*ws_count;
    for (int j = gw; j < nf; j += NW) {
        const int pt = ws_list[j];
        const int k1 = recompute_point(X, mus, pt, l);
        if (l == 0) out[pt] = k1;
    }
}

// Fallback scan fixup (flag bit 31 in out), used if ws too small.
__global__ void __launch_bounds__(256)
fixup_scan_kernel(const float* __restrict__ X, const float* __restrict__ mus,
                  int* __restrict__ out, int n) {
    const int gw = (int)((blockIdx.x * blockDim.x + threadIdx.x) >> 6);
    const int l  = threadIdx.x & 63;
    const int NW = (int)((gridDim.x * blockDim.x) >> 6);
    const int chunk = (n + NW - 1) / NW;
    const int base = gw * chunk;
    const int end  = (base + chunk < n) ? (base + chunk) : n;
    for (int s = base; s < end; s += 64) {
        const int i = s + l;
        const int v = (i < end) ? out[i] : 0;
        const bool fl = (i < end) && ((unsigned)v & 0x80000000u);
        unsigned long long m = __ballot(fl);
        while (m) {
            const int src = (int)__ffsll((unsigned long long)m) - 1;
            m &= m - 1;
            const int pt = __shfl(i, src);
            const int k1 = recompute_point(X, mus, pt, l);
            if (l == 0) out[pt] = k1;
        }
    }
}

extern "C" void kernel_launch(void* const* d_in, const int* in_sizes, int n_in,
                              void* d_out, int out_size, void* d_ws, size_t ws_size,
                              hipStream_t stream) {
    const float* X = (const float*)d_in[0];
    const float* mus = (const float*)d_in[1];
    int* out = (int*)d_out;
    const int n = in_sizes[0] / DIM;  // 500000

    unsigned* ws_count = (unsigned*)d_ws;
    int* ws_list = (int*)((char*)d_ws + 16);
    const int use_list = (ws_size >= 16 + (size_t)n * 4) ? 1 : 0;

    if (use_list) {
        hipMemsetAsync(d_ws, 0, 16, stream);  // reset append counter
    }

    argmin_mfma_kernel<<<NBLK, 256, 0, stream>>>(X, mus, out, ws_count,
                                                 ws_list, use_list, n);
    if (use_list) {
        fixup_list_kernel<<<512, 256, 0, stream>>>(X, mus, ws_count, ws_list,
                                                   out);
    } else {
        fixup_scan_kernel<<<512, 256, 0, stream>>>(X, mus, out, n);
    }
}